// Round 8
// baseline (666.239 us; speedup 1.0000x reference)
//
#include <hip/hip_runtime.h>
#include <hip/hip_cooperative_groups.h>
#include <math.h>

namespace cg = cooperative_groups;

#define EDIM 128
#define NHEAD 16
#define HDIM 8
#define SEQ 2048
#define BATCH 4
#define NROW (BATCH*SEQ)            // 8192
// -scale*log2(e): folded into Q at projection time so sigmoid = rcp(1+exp2(dot))
#define QNEG (-0.35355339059327373f * 1.4426950408889634f)

#if __has_builtin(__builtin_amdgcn_exp2f)
#define EXP2F(x) __builtin_amdgcn_exp2f(x)
#else
#define EXP2F(x) exp2f(x)
#endif
#define RCPF(x) __builtin_amdgcn_rcpf(x)

typedef __attribute__((ext_vector_type(8))) short short8v;
typedef __attribute__((ext_vector_type(4))) short short4v;
typedef __attribute__((ext_vector_type(4))) float float4v;

union U16x8 { uint4 u; short8v s; };
union U16x4 { uint2 u; short4v s; };

#if __has_builtin(__builtin_amdgcn_mfma_f32_16x16x16bf16_1k)
#define MFMA_PV(a,b,c) __builtin_amdgcn_mfma_f32_16x16x16bf16_1k(a,b,c,0,0,0)
#else
static __device__ __forceinline__ float4v mfma_pv_asm(short4v a, short4v b, float4v c) {
  float4v d;
  asm("v_mfma_f32_16x16x16_bf16 %0, %1, %2, %3" : "=v"(d) : "v"(a), "v"(b), "v"(c));
  return d;
}
#define MFMA_PV(a,b,c) mfma_pv_asm(a,b,c)
#endif

// pack two floats to bf16x2, round-to-nearest-even-ish (values finite)
__device__ __forceinline__ unsigned pk_bf16(float a, float b) {
  unsigned ua = __float_as_uint(a), ub = __float_as_uint(b);
  unsigned lo = (ua + 0x7fffu + ((ua >> 16) & 1u)) >> 16;
  unsigned hi = (ub + 0x7fffu + ((ub >> 16) & 1u)) & 0xffff0000u;
  return lo | hi;
}

// ---------------------------------------------------------------------------
// W cast body: gtid < 16384 casts one float4 chunk of one matrix to bf16
// (Wb layout: [4][128][128] row-major, un-transposed — B-frag reads rows).
// ---------------------------------------------------------------------------
__device__ __forceinline__
void cast_body(const float* __restrict__ Wq, const float* __restrict__ Wk,
               const float* __restrict__ Wv, const float* __restrict__ Wo,
               unsigned short* __restrict__ Wb, int gtid)
{
  if (gtid >= 16384) return;
  const float* W = (gtid < 4096) ? Wq : (gtid < 8192) ? Wk
                 : (gtid < 12288) ? Wv : Wo;
  const int i = (gtid & 4095) * 4;
  const float4 f = *(const float4*)(W + i);
  uint2 p;
  p.x = pk_bf16(f.x, f.y);
  p.y = pk_bf16(f.z, f.w);
  *(uint2*)(Wb + (size_t)(gtid >> 12) * (EDIM * EDIM) + i) = p;
}

// ---------------------------------------------------------------------------
// stage 16 rows of fp32 src as bf16 into XOR-swizzled LDS (4 KB)
// ---------------------------------------------------------------------------
__device__ __forceinline__
void stage16(const float* __restrict__ X, unsigned short* xs, int row0, int tid)
{
  const int r = tid >> 4, c16 = tid & 15;
  const float4* src = (const float4*)(X + (size_t)(row0 + r) * EDIM + c16 * 8);
  const float4 f0 = src[0], f1 = src[1];
  uint4 v;
  v.x = pk_bf16(f0.x, f0.y); v.y = pk_bf16(f0.z, f0.w);
  v.z = pk_bf16(f1.x, f1.y); v.w = pk_bf16(f1.z, f1.w);
  const unsigned addr = (unsigned)(r * 256 + c16 * 16) ^ (unsigned)((r & 7) << 4);
  *(uint4*)((char*)xs + addr) = v;
}

// A-frags from swizzled LDS: A lane l: A[m=l&15][k=(l>>4)*8+j]
__device__ __forceinline__
void afrags(const unsigned short* xs, int lq, int qd, short8v a[4])
{
  #pragma unroll
  for (int kk = 0; kk < 4; ++kk) {
    const unsigned addr =
        (unsigned)(lq * 256 + kk * 64 + qd * 16) ^ (unsigned)((lq & 7) << 4);
    a[kk] = *(const short8v*)((const char*)xs + addr);
  }
}

// ---------------------------------------------------------------------------
// One 16-row x 16-col projection subtile (1 D-tile, 4 MFMA over K=128).
//   B lane l: B[k=(l>>4)*8+j][n=l&15] = Wb[n_g][k]  (16B contiguous loads)
//   D lane l: D[m=(l>>4)*4+r][n=l&15]
// MODE 0: Q*QNEG -> bf16 [bh][s][8]    MODE 1: K -> bf16 [bh][s][8]
// MODE 2: V -> Vt[bh][t=s>>4][d][si]   MODE 3: fp32 [rows][128]
// ---------------------------------------------------------------------------
template<int MODE>
__device__ __forceinline__
void proj_subtile(const short8v a[4], const unsigned short* __restrict__ Wbm,
                  const float* __restrict__ bias, void* __restrict__ out,
                  int row0, int lq, int qd, int c16)
{
  const int ng = c16 * 16 + lq;
  float4v D = {0.f, 0.f, 0.f, 0.f};
  const unsigned short* wr = Wbm + (size_t)ng * EDIM + qd * 8;
  #pragma unroll
  for (int kk = 0; kk < 4; ++kk) {
    U16x8 b; b.u = *(const uint4*)(wr + kk * 32);
    D = __builtin_amdgcn_mfma_f32_16x16x32_bf16(a[kk], b.s, D, 0, 0, 0);
  }
  const float bz = bias[ng];

  if (MODE == 3) {
    float* of = (float*)out + (size_t)(row0 + qd * 4) * EDIM + ng;
    #pragma unroll
    for (int r = 0; r < 4; ++r) of[r * EDIM] = D[r] + bz;
    return;
  }

  const int b_ = row0 >> 11;
  const int bh = b_ * NHEAD + (ng >> 3), dv = ng & 7;
  unsigned short* oU = (unsigned short*)out;

  if (MODE == 2) {
    const int tg = (row0 & (SEQ - 1)) >> 4;       // row0 is 16-aligned
    uint2 p;
    p.x = pk_bf16(D[0] + bz, D[1] + bz);
    p.y = pk_bf16(D[2] + bz, D[3] + bz);
    *(uint2*)(oU + (size_t)bh * (SEQ * HDIM) + tg * 128 + dv * 16 + qd * 4) = p;
    return;
  }

  const int srel = (row0 & (SEQ - 1)) + qd * 4;
  unsigned short* pA = oU + ((size_t)bh * SEQ + srel) * 8 + dv;
  #pragma unroll
  for (int r = 0; r < 4; ++r) {
    float v = D[r] + bz;
    if (MODE == 0) v *= QNEG;
    pA[r * 8] = (unsigned short)pk_bf16(v, 0.f);
  }
}

// ---------------------------------------------------------------------------
// QKV block work: block pair (bid>>1 = row-tile rt, bid&1 = half) covers the
// 24 16-col subtiles (3 matrices x 8 col-groups) with 8 waves x 3 subtiles.
// ---------------------------------------------------------------------------
__device__ __forceinline__
void qkv_block(const float* __restrict__ X, const unsigned short* __restrict__ Wb,
               const float* __restrict__ bq, const float* __restrict__ bk,
               const float* __restrict__ bv,
               unsigned* __restrict__ qb, unsigned* __restrict__ kb,
               unsigned* __restrict__ vb,
               unsigned short* xs, int bid, int tid)
{
  const int row0 = (bid >> 1) * 16;
  stage16(X, xs, row0, tid);
  __syncthreads();
  const int lane = tid & 63, wv = tid >> 6;
  const int lq = lane & 15, qd = lane >> 4;
  short8v a[4];
  afrags(xs, lq, qd, a);
  const int ws_ = (bid & 1) * 4 + wv;             // 0..7
  #pragma unroll
  for (int i = 0; i < 3; ++i) {
    const int s = ws_ * 3 + i;                    // 0..23
    const int m = s >> 3, c16 = s & 7;
    const unsigned short* wbm = Wb + (size_t)m * (EDIM * EDIM);
    if (m == 0)      proj_subtile<0>(a, wbm, bq, (void*)qb, row0, lq, qd, c16);
    else if (m == 1) proj_subtile<1>(a, wbm, bk, (void*)kb, row0, lq, qd, c16);
    else             proj_subtile<2>(a, wbm, bv, (void*)vb, row0, lq, qd, c16);
  }
}

__device__ __forceinline__
void oproj_block(const float* __restrict__ A, const unsigned short* __restrict__ Wbo,
                 const float* __restrict__ bo, float* __restrict__ out,
                 unsigned short* xs, int bid, int tid)
{
  const int row0 = bid * 16;
  stage16(A, xs, row0, tid);
  __syncthreads();
  const int lane = tid & 63, wv = tid >> 6;
  const int lq = lane & 15, qd = lane >> 4;
  short8v a[4];
  afrags(xs, lq, qd, a);
  proj_subtile<3>(a, Wbo, bo, (void*)out, row0, lq, qd, wv * 2 + 0);
  proj_subtile<3>(a, Wbo, bo, (void*)out, row0, lq, qd, wv * 2 + 1);
}

// ---------------------------------------------------------------------------
// Attention (math byte-identical to the 42.6us v11 kernel).
// ---------------------------------------------------------------------------
template<bool DIAG>
__device__ __forceinline__
float4v attn_step(short8v kf, short8v qf, short4v vf, float4v acc,
                  int laneq, int quad)
{
  const float4v z = {0.f, 0.f, 0.f, 0.f};
  float4v st = __builtin_amdgcn_mfma_f32_16x16x32_bf16(kf, qf, z, 0, 0, 0);
  unsigned rb[4];
  #pragma unroll
  for (int r = 0; r < 4; ++r) {
    float s = RCPF(1.f + EXP2F(st[r]));           // Q carries -scale*log2e
    if (DIAG) s = (4 * quad + r <= laneq) ? s : 0.f;  // exact: sigma(-1e9)==0
    rb[r] = __float_as_uint(s) + 0x8000u;         // round-half-up to bf16
  }
  U16x4 p;
  p.u.x = __builtin_amdgcn_perm(rb[1], rb[0], 0x07060302u);
  p.u.y = __builtin_amdgcn_perm(rb[3], rb[2], 0x07060302u);
  return MFMA_PV(p.s, vf, acc);                   // A = P[q][k], B = V[k][d]
}

__device__ __forceinline__
short4v load_vfrag(const unsigned short* __restrict__ Vtbh, int t,
                   int quad, int d, bool is8)
{
  const unsigned short* p = Vtbh + t * 128 + d * 16 + 4 * quad;
  const uint2 v = *(const uint2*)p;
  U16x4 vf;
  vf.u.x = is8 ? 0x3F803F80u : v.x;
  vf.u.y = is8 ? 0x3F803F80u : v.y;
  return vf.s;
}

__device__ __forceinline__
void attn_epilogue(float4v acc, int T, int bh, int laneq, int quad,
                   float* __restrict__ out)
{
  const int b_ = bh >> 4, h = bh & 15;
  const int pidx = (quad * 16 + 8) << 2;          // lane holding col 8
  #pragma unroll
  for (int r = 0; r < 4; ++r) {
    const float den = __int_as_float(
        __builtin_amdgcn_ds_bpermute(pidx, __float_as_int(acc[r])));
    const float val = acc[r] * RCPF(den);         // den > 0
    const int row = 16 * T + 4 * quad + r;
    if (laneq < 8)
      out[(size_t)(b_ * SEQ + row) * EDIM + h * HDIM + laneq] = val;
  }
}

// One attn task on a 128-thread group. cmb = 512 floats (2 KB) for this group.
// Contains 2 block-wide barriers (uniform count for all callers).
__device__ void attn_task(const unsigned* __restrict__ Qb,
                          const unsigned* __restrict__ Kb,
                          const unsigned* __restrict__ Vb,
                          float* __restrict__ out,
                          int task, int t128, float* cmb)
{
  const int bh    = task & 63;
  const int g     = (task >> 6) & 63;
  const int w     = t128 >> 6;
  const int lane  = t128 & 63;
  const int laneq = lane & 15;
  const int quad  = lane >> 4;
  const int L = g, H = 127 - g;
  const int mL = (L + 1) >> 1, mH = (H + 1) >> 1;
  const int d   = laneq & 7;
  const bool is8 = (laneq == 8);

  const uint4* Kg = (const uint4*)Kb + (size_t)bh * 2048;
  const uint4* Qg = (const uint4*)Qb + (size_t)bh * 2048;
  const unsigned short* Vtbh = (const unsigned short*)Vb + (size_t)bh * SEQ * HDIM;

  U16x8 qfl, qfh;
  {
    const uint4 rl = Qg[16 * L + laneq];
    const uint4 rh = Qg[16 * H + laneq];
    qfl.u = (lane < 16) ? rl : make_uint4(0u, 0u, 0u, 0u);
    qfh.u = (lane < 16) ? rh : make_uint4(0u, 0u, 0u, 0u);
  }

  float4v accL = {0.f, 0.f, 0.f, 0.f};
  float4v accH = {0.f, 0.f, 0.f, 0.f};

  if (w == 0) {
    U16x8 kf; kf.u = Kg[laneq];
    short4v vf = load_vfrag(Vtbh, 0, quad, d, is8);
    #pragma unroll 2
    for (int t = 0; t < mH; ++t) {
      U16x8 kn; kn.u = Kg[16 * (t + 1) + laneq];
      short4v vn = load_vfrag(Vtbh, t + 1, quad, d, is8);
      if (t < mL) accL = attn_step<false>(kf.s, qfl.s, vf, accL, laneq, quad);
      accH = attn_step<false>(kf.s, qfh.s, vf, accH, laneq, quad);
      kf = kn; vf = vn;
    }
  } else {
    U16x8 kf; kf.u = Kg[16 * mL + laneq];
    short4v vf = load_vfrag(Vtbh, mL, quad, d, is8);
    #pragma unroll 2
    for (int t = mL; t < L; ++t) {
      U16x8 kn; kn.u = Kg[16 * (t + 1) + laneq];
      short4v vn = load_vfrag(Vtbh, t + 1, quad, d, is8);
      accL = attn_step<false>(kf.s, qfl.s, vf, accL, laneq, quad);
      kf = kn; vf = vn;
    }
    accL = attn_step<true>(kf.s, qfl.s, vf, accL, laneq, quad);
    kf.u = Kg[16 * mH + laneq];
    vf = load_vfrag(Vtbh, mH, quad, d, is8);
    #pragma unroll 2
    for (int t = mH; t < H; ++t) {
      U16x8 kn; kn.u = Kg[16 * (t + 1) + laneq];
      short4v vn = load_vfrag(Vtbh, t + 1, quad, d, is8);
      accH = attn_step<false>(kf.s, qfh.s, vf, accH, laneq, quad);
      kf = kn; vf = vn;
    }
    accH = attn_step<true>(kf.s, qfh.s, vf, accH, laneq, quad);

    *(float4*)(cmb + lane * 4)       = make_float4(accL[0], accL[1], accL[2], accL[3]);
    *(float4*)(cmb + 256 + lane * 4) = make_float4(accH[0], accH[1], accH[2], accH[3]);
  }
  __syncthreads();

  if (w == 0) {
    const float4 pL = *(const float4*)(cmb + lane * 4);
    const float4 pH = *(const float4*)(cmb + 256 + lane * 4);
    accL[0] += pL.x; accL[1] += pL.y; accL[2] += pL.z; accL[3] += pL.w;
    accH[0] += pH.x; accH[1] += pH.y; accH[2] += pH.z; accH[3] += pH.w;
    attn_epilogue(accL, L, bh, laneq, quad, out);
    attn_epilogue(accH, H, bh, laneq, quad, out);
  }
  __syncthreads();                                // cmb reuse guard
}

// ---------------------------------------------------------------------------
// MEGA: all 4 phases in one cooperative kernel. 1024 blocks x 256 thr,
// __launch_bounds__(256,4) -> <=128 VGPR -> exactly 4 blocks/CU co-resident.
// ---------------------------------------------------------------------------
__global__ __launch_bounds__(256, 4)
void mega_kernel(const float* __restrict__ X,
                 const float* __restrict__ Wq, const float* __restrict__ Wk,
                 const float* __restrict__ Wv, const float* __restrict__ Wo,
                 const float* __restrict__ bq, const float* __restrict__ bk,
                 const float* __restrict__ bv, const float* __restrict__ bo,
                 unsigned short* __restrict__ Wb, float* __restrict__ attnbuf,
                 unsigned* __restrict__ Qb, unsigned* __restrict__ Kb,
                 unsigned* __restrict__ Vb, float* __restrict__ out)
{
  __shared__ __align__(16) unsigned short smem[2048];   // 4 KB, reused per phase
  const int tid = threadIdx.x, bid = blockIdx.x;
  cg::grid_group grid = cg::this_grid();

  // phase 0: cast W -> bf16
  cast_body(Wq, Wk, Wv, Wo, Wb, bid * 256 + tid);
  __threadfence();
  grid.sync();

  // phase 1: QKV projections
  qkv_block(X, Wb, bq, bk, bv, Qb, Kb, Vb, smem, bid, tid);
  __threadfence();
  grid.sync();

  // phase 2: attention — 2 independent 128-thr halves x 2 sequential tasks
  {
    float* cmb = (float*)smem + (tid >> 7) * 512;
    const int t128 = tid & 127;
    const int slot = bid * 2 + (tid >> 7);        // 0..2047
    attn_task(Qb, Kb, Vb, attnbuf, slot,        t128, cmb);
    attn_task(Qb, Kb, Vb, attnbuf, 2048 + slot, t128, cmb);
  }
  __threadfence();
  grid.sync();

  // phase 3: output projection (blocks 0..511)
  if (bid < 512)
    oproj_block(attnbuf, Wb + 3 * (EDIM * EDIM), bo, out, smem, bid, tid);
}

// ---------------------------------------------------------------------------
// Fallback discrete kernels (same device code), used if cooperative launch
// is unavailable. Numerically identical to the mega path.
// ---------------------------------------------------------------------------
__global__ __launch_bounds__(256)
void cast_kernel(const float* __restrict__ Wq, const float* __restrict__ Wk,
                 const float* __restrict__ Wv, const float* __restrict__ Wo,
                 unsigned short* __restrict__ Wb)
{
  cast_body(Wq, Wk, Wv, Wo, Wb, blockIdx.x * 256 + threadIdx.x);
}

__global__ __launch_bounds__(256)
void qkv_kernel(const float* __restrict__ X, const unsigned short* __restrict__ Wb,
                const float* __restrict__ bq, const float* __restrict__ bk,
                const float* __restrict__ bv,
                unsigned* __restrict__ qb, unsigned* __restrict__ kb,
                unsigned* __restrict__ vb)
{
  __shared__ __align__(16) unsigned short xs[2048];
  qkv_block(X, Wb, bq, bk, bv, qb, kb, vb, xs, blockIdx.x, threadIdx.x);
}

__global__ __launch_bounds__(128, 8)
void attn_kernel(const unsigned* __restrict__ Qb, const unsigned* __restrict__ Kb,
                 const unsigned* __restrict__ Vb, float* __restrict__ out)
{
  __shared__ __align__(16) float cmb[512];
  attn_task(Qb, Kb, Vb, out, blockIdx.x, threadIdx.x, cmb);
}

__global__ __launch_bounds__(256)
void oproj_kernel(const float* __restrict__ A, const unsigned short* __restrict__ Wbo,
                  const float* __restrict__ bo, float* __restrict__ out)
{
  __shared__ __align__(16) unsigned short xs[2048];
  oproj_block(A, Wbo, bo, out, xs, blockIdx.x, threadIdx.x);
}

// ---------------------------------------------------------------------------
extern "C" void kernel_launch(void* const* d_in, const int* in_sizes, int n_in,
                              void* d_out, int out_size, void* d_ws, size_t ws_size,
                              hipStream_t stream)
{
  const float* x  = (const float*)d_in[0];
  const float* Wq = (const float*)d_in[1];
  const float* bq = (const float*)d_in[2];
  const float* Wk = (const float*)d_in[3];
  const float* bk = (const float*)d_in[4];
  const float* Wv = (const float*)d_in[5];
  const float* bv = (const float*)d_in[6];
  const float* Wo = (const float*)d_in[7];
  const float* bo = (const float*)d_in[8];
  float* outp = (float*)d_out;

  float* ws = (float*)d_ws;
  // layout: Wb bf16 4x128x128 (128KB, in reserved 256KB) | attn 1048576 f |
  //         Qb, Kb, Vt 524288 dwords each
  unsigned short* Wb = (unsigned short*)ws;
  float*    attn = ws + 65536;
  unsigned* Qb   = (unsigned*)(ws + 65536 + 1048576);
  unsigned* Kb   = Qb + (size_t)524288;
  unsigned* Vb   = Kb + (size_t)524288;

  void* args[] = {
    (void*)&x, (void*)&Wq, (void*)&Wk, (void*)&Wv, (void*)&Wo,
    (void*)&bq, (void*)&bk, (void*)&bv, (void*)&bo,
    (void*)&Wb, (void*)&attn, (void*)&Qb, (void*)&Kb, (void*)&Vb, (void*)&outp
  };
  hipError_t e = hipLaunchCooperativeKernel((void*)mega_kernel, dim3(1024),
                                            dim3(256), args, 0, stream);
  if (e != hipSuccess) {
    // fallback: same device code as 4 discrete launches
    cast_kernel<<<dim3(64), 256, 0, stream>>>(Wq, Wk, Wv, Wo, Wb);
    qkv_kernel<<<dim3(1024), 256, 0, stream>>>(x, Wb, bq, bk, bv, Qb, Kb, Vb);
    attn_kernel<<<dim3(4096), 128, 0, stream>>>(Qb, Kb, Vb, attn);
    oproj_kernel<<<dim3(512), 256, 0, stream>>>(attn, Wb + 3 * EDIM * EDIM, bo, outp);
  }
}

// Round 9
// 123.124 us; speedup vs baseline: 5.4111x; 5.4111x over previous
//
#include <hip/hip_runtime.h>
#include <math.h>

#define EDIM 128
#define NHEAD 16
#define HDIM 8
#define SEQ 2048
#define BATCH 4
#define NROW (BATCH*SEQ)            // 8192
// -scale*log2(e): folded into Q at projection time so sigmoid = rcp(1+exp2(dot))
#define QNEG (-0.35355339059327373f * 1.4426950408889634f)

#if __has_builtin(__builtin_amdgcn_exp2f)
#define EXP2F(x) __builtin_amdgcn_exp2f(x)
#else
#define EXP2F(x) exp2f(x)
#endif
#define RCPF(x) __builtin_amdgcn_rcpf(x)

typedef __attribute__((ext_vector_type(8))) short short8v;
typedef __attribute__((ext_vector_type(4))) short short4v;
typedef __attribute__((ext_vector_type(4))) float float4v;

union U16x8 { uint4 u; short8v s; };
union U16x4 { uint2 u; short4v s; };

#if __has_builtin(__builtin_amdgcn_mfma_f32_16x16x16bf16_1k)
#define MFMA_PV(a,b,c) __builtin_amdgcn_mfma_f32_16x16x16bf16_1k(a,b,c,0,0,0)
#else
static __device__ __forceinline__ float4v mfma_pv_asm(short4v a, short4v b, float4v c) {
  float4v d;
  asm("v_mfma_f32_16x16x16_bf16 %0, %1, %2, %3" : "=v"(d) : "v"(a), "v"(b), "v"(c));
  return d;
}
#define MFMA_PV(a,b,c) mfma_pv_asm(a,b,c)
#endif

// pack two floats to bf16x2, round-to-nearest-even-ish (values finite)
__device__ __forceinline__ unsigned pk_bf16(float a, float b) {
  unsigned ua = __float_as_uint(a), ub = __float_as_uint(b);
  unsigned lo = (ua + 0x7fffu + ((ua >> 16) & 1u)) >> 16;
  unsigned hi = (ub + 0x7fffu + ((ub >> 16) & 1u)) & 0xffff0000u;
  return lo | hi;
}

// ---------------------------------------------------------------------------
// Cast the 4 weight matrices to bf16, un-transposed [4][128][128].
// ---------------------------------------------------------------------------
__global__ __launch_bounds__(256)
void cast4_kernel(const float* __restrict__ W0, const float* __restrict__ W1,
                  const float* __restrict__ W2, const float* __restrict__ W3,
                  unsigned short* __restrict__ Wb)
{
  const float* W = (blockIdx.y == 0) ? W0 : (blockIdx.y == 1) ? W1
                 : (blockIdx.y == 2) ? W2 : W3;
  unsigned short* o = Wb + (size_t)blockIdx.y * (EDIM * EDIM);
  const int i = (blockIdx.x * 256 + threadIdx.x) * 4;
  const float4 f = *(const float4*)(W + i);
  uint2 p;
  p.x = pk_bf16(f.x, f.y);
  p.y = pk_bf16(f.z, f.w);
  *(uint2*)(o + i) = p;
}

// ---------------------------------------------------------------------------
// stage 16 rows of fp32 src as bf16 into XOR-swizzled LDS (4 KB)
// ---------------------------------------------------------------------------
__device__ __forceinline__
void stage16(const float* __restrict__ X, unsigned short* xs, int row0, int tid)
{
  const int r = tid >> 4, c16 = tid & 15;
  const float4* src = (const float4*)(X + (size_t)(row0 + r) * EDIM + c16 * 8);
  const float4 f0 = src[0], f1 = src[1];
  uint4 v;
  v.x = pk_bf16(f0.x, f0.y); v.y = pk_bf16(f0.z, f0.w);
  v.z = pk_bf16(f1.x, f1.y); v.w = pk_bf16(f1.z, f1.w);
  const unsigned addr = (unsigned)(r * 256 + c16 * 16) ^ (unsigned)((r & 7) << 4);
  *(uint4*)((char*)xs + addr) = v;
}

// A-frags from swizzled LDS: A lane l: A[m=l&15][k=(l>>4)*8+j]
__device__ __forceinline__
void afrags(const unsigned short* xs, int lq, int qd, short8v a[4])
{
  #pragma unroll
  for (int kk = 0; kk < 4; ++kk) {
    const unsigned addr =
        (unsigned)(lq * 256 + kk * 64 + qd * 16) ^ (unsigned)((lq & 7) << 4);
    a[kk] = *(const short8v*)((const char*)xs + addr);
  }
}

// ---------------------------------------------------------------------------
// MFMA projection, 16 rows x 128 cols per 256-thr block; wave wv owns cols
// [32wv, 32wv+32) as two 16-col D-tiles (8 MFMA/wave over K=128).
//   B lane l: B[k=(l>>4)*8+j][n=l&15] = Wb[n][k]   D lane l: D[(l>>4)*4+r][l&15]
// MODE 0: Q*QNEG -> bf16 [bh][s][8]   (NEW: per-wave LDS bounce -> 256B
// MODE 1: K      -> bf16 [bh][s][8]    contiguous uint4 stores, replacing the
//                                      old per-lane 2B scattered stores)
// MODE 2: V -> Vt[bh][t=s>>4][d][si]  (already coalesced)
// MODE 3: fp32 [rows][128] (final output)
// bnc: this wave's 640-u16 ([2][16][20]) bounce region (MODE 0/1 only).
// ---------------------------------------------------------------------------
template<int MODE>
__device__ __forceinline__
void proj_mfma(const float* __restrict__ X, const unsigned short* __restrict__ Wbm,
               const float* __restrict__ bias, void* __restrict__ out,
               int row0, int tid, unsigned short* xs, unsigned short* bnc)
{
  stage16(X, xs, row0, tid);
  __syncthreads();

  const int lane = tid & 63, wv = tid >> 6;
  const int lq = lane & 15, qd = lane >> 4;
  const int n0 = wv * 32;
  short8v a[4];
  afrags(xs, lq, qd, a);

  float4v D0 = {0.f, 0.f, 0.f, 0.f}, D1 = {0.f, 0.f, 0.f, 0.f};
  const unsigned short* wr0 = Wbm + (size_t)(n0 + lq) * EDIM + qd * 8;
  #pragma unroll
  for (int kk = 0; kk < 4; ++kk) {
    U16x8 b0, b1;
    b0.u = *(const uint4*)(wr0 + kk * 32);
    b1.u = *(const uint4*)(wr0 + 16 * EDIM + kk * 32);
    D0 = __builtin_amdgcn_mfma_f32_16x16x32_bf16(a[kk], b0.s, D0, 0, 0, 0);
    D1 = __builtin_amdgcn_mfma_f32_16x16x32_bf16(a[kk], b1.s, D1, 0, 0, 0);
  }

  const int nA = n0 + lq, nB = nA + 16;
  const float bzA = bias[nA], bzB = bias[nB];

  if (MODE == 3) {
    float* of = (float*)out + (size_t)(row0 + qd * 4) * EDIM + nA;
    #pragma unroll
    for (int r = 0; r < 4; ++r) {
      of[r * EDIM]      = D0[r] + bzA;
      of[r * EDIM + 16] = D1[r] + bzB;
    }
    return;
  }

  const int b_ = row0 >> 11, srel0 = row0 & (SEQ - 1);

  if (MODE == 2) {
    // Vt[bh][tg][d][si]: block = one 16-s tile; si = qd*4 + r. Coalesced.
    const int tg = srel0 >> 4;
    unsigned short* oU = (unsigned short*)out;
    {
      const int bh = b_ * NHEAD + (nA >> 3), dv = nA & 7;
      uint2 p;
      p.x = pk_bf16(D0[0] + bzA, D0[1] + bzA);
      p.y = pk_bf16(D0[2] + bzA, D0[3] + bzA);
      *(uint2*)(oU + (size_t)bh * (SEQ * HDIM) + tg * 128 + dv * 16 + qd * 4) = p;
    }
    {
      const int bh = b_ * NHEAD + (nB >> 3), dv = nB & 7;
      uint2 p;
      p.x = pk_bf16(D1[0] + bzB, D1[1] + bzB);
      p.y = pk_bf16(D1[2] + bzB, D1[3] + bzB);
      *(uint2*)(oU + (size_t)bh * (SEQ * HDIM) + tg * 128 + dv * 16 + qd * 4) = p;
    }
    return;
  }

  // MODE 0/1: bounce both 16x16 tiles through padded LDS ([16][20] u16 each;
  // write banks verified conflict-free, read <=2-way), then store contiguous
  // 256B per (tile,half): uint4 = one [bh][s][8] row per lane.
  #pragma unroll
  for (int r = 0; r < 4; ++r) {
    float vA = D0[r] + bzA, vB = D1[r] + bzB;
    if (MODE == 0) { vA *= QNEG; vB *= QNEG; }
    const int m = qd * 4 + r;
    bnc[m * 20 + lq]       = (unsigned short)pk_bf16(vA, 0.f);
    bnc[320 + m * 20 + lq] = (unsigned short)pk_bf16(vB, 0.f);
  }
  __syncthreads();                                // order LDS write->read

  const int mm   = lane & 15;
  const int half = (lane >> 4) & 1;
  const int tile = lane >> 5;
  const unsigned short* sp = bnc + tile * 320 + mm * 20 + half * 8;
  const uint2 w0 = *(const uint2*)sp;
  const uint2 w1 = *(const uint2*)(sp + 4);
  const int bh = b_ * NHEAD + wv * 4 + tile * 2 + half;
  unsigned short* dp = (unsigned short*)out + ((size_t)bh * SEQ + srel0 + mm) * 8;
  *(uint4*)dp = make_uint4(w0.x, w0.y, w1.x, w1.y);
}

__global__ __launch_bounds__(256)
void qkv_kernel(const float* __restrict__ X, const unsigned short* __restrict__ Wb,
                const float* __restrict__ bq, const float* __restrict__ bk,
                const float* __restrict__ bv,
                unsigned* __restrict__ qb, unsigned* __restrict__ kb,
                unsigned* __restrict__ vb)
{
  __shared__ __align__(16) unsigned short xs[2048];      // 4 KB
  __shared__ __align__(16) unsigned short bnc[4 * 640];  // 5 KB (per-wave 640)
  const int tid = threadIdx.x;
  const int row0 = blockIdx.x * 16;
  unsigned short* myb = bnc + (tid >> 6) * 640;
  const int m = blockIdx.y;
  const unsigned short* wb = Wb + (size_t)m * EDIM * EDIM;
  if (m == 0)      proj_mfma<0>(X, wb, bq, (void*)qb, row0, tid, xs, myb);
  else if (m == 1) proj_mfma<1>(X, wb, bk, (void*)kb, row0, tid, xs, myb);
  else             proj_mfma<2>(X, wb, bv, (void*)vb, row0, tid, xs, myb);
}

__global__ __launch_bounds__(256)
void oproj_kernel(const float* __restrict__ A, const unsigned short* __restrict__ Wbo,
                  const float* __restrict__ bo, float* __restrict__ out)
{
  __shared__ __align__(16) unsigned short xs[2048];      // 4 KB
  proj_mfma<3>(A, Wbo, bo, (void*)out, blockIdx.x * 16, threadIdx.x, xs, nullptr);
}

// ---------------------------------------------------------------------------
// One 16q x 16k MFMA step.  (round-0 verified sigmoid path)
// S^T = mfma_16x16x32_bf16(A=K-rows, B=Q-frag) -> C[key][q]. Sigmoid
// elementwise; C-register reinterpreted as A-operand of mfma_16x16x16 gives
// the UN-transposed P, so out[q][d] = mfma(A=P, B=V-frag, acc). V-frag col 8
// is forced to 1.0 so acc col 8 accumulates the denominator.
// ---------------------------------------------------------------------------
template<bool DIAG>
__device__ __forceinline__
float4v attn_step(short8v kf, short8v qf, short4v vf, float4v acc,
                  int laneq, int quad)
{
  const float4v z = {0.f, 0.f, 0.f, 0.f};
  float4v st = __builtin_amdgcn_mfma_f32_16x16x32_bf16(kf, qf, z, 0, 0, 0);
  unsigned rb[4];
  #pragma unroll
  for (int r = 0; r < 4; ++r) {
    float s = RCPF(1.f + EXP2F(st[r]));           // Q carries -scale*log2e
    if (DIAG) s = (4 * quad + r <= laneq) ? s : 0.f;  // exact: sigma(-1e9)==0
    rb[r] = __float_as_uint(s) + 0x8000u;         // round-half-up to bf16
  }
  U16x4 p;
  p.u.x = __builtin_amdgcn_perm(rb[1], rb[0], 0x07060302u);
  p.u.y = __builtin_amdgcn_perm(rb[3], rb[2], 0x07060302u);
  return MFMA_PV(p.s, vf, acc);                   // A = P[q][k], B = V[k][d]
}

// V-frag loader from tile-blocked Vt[bh][t][d][si]: ONE dwordx2 from a
// contiguous 256B tile block. lanes laneq==8 -> bf16 1.0 (denominator col).
__device__ __forceinline__
short4v load_vfrag(const unsigned short* __restrict__ Vtbh, int t,
                   int quad, int d, bool is8)
{
  const unsigned short* p = Vtbh + t * 128 + d * 16 + 4 * quad;
  const uint2 v = *(const uint2*)p;
  U16x4 vf;
  vf.u.x = is8 ? 0x3F803F80u : v.x;
  vf.u.y = is8 ? 0x3F803F80u : v.y;
  return vf.s;
}

// epilogue: den = acc col 8; normalize and store rows of tile T
__device__ __forceinline__
void epilogue(float4v acc, int T, int bh, int laneq, int quad,
              float* __restrict__ out)
{
  const int b_ = bh >> 4, h = bh & 15;
  const int pidx = (quad * 16 + 8) << 2;          // lane holding col 8
  #pragma unroll
  for (int r = 0; r < 4; ++r) {
    const float den = __int_as_float(
        __builtin_amdgcn_ds_bpermute(pidx, __float_as_int(acc[r])));
    const float val = acc[r] * RCPF(den);         // den > 0
    const int row = 16 * T + 4 * quad + r;
    if (laneq < 8)
      out[(size_t)(b_ * SEQ + row) * EDIM + h * HDIM + laneq] = val;
  }
}

// ---------------------------------------------------------------------------
// Causal sigmoid-attention v11 (unchanged control: 42.6us): split-K x2
// fold-pair schedule, dwordx2 V-frags from tile-blocked Vt.
// blockIdx low 6 bits = bh -> XCD = bh%8 (L2 locality).
// ---------------------------------------------------------------------------
__global__ __launch_bounds__(128, 8)
void attn_kernel(const unsigned* __restrict__ Qb, const unsigned* __restrict__ Kb,
                 const unsigned* __restrict__ Vb, float* __restrict__ out)
{
  __shared__ float cmb[2][64][4];                 // 2 KB

  const int bh    = blockIdx.x & 63;
  const int g     = blockIdx.x >> 6;              // 0..63
  const int w     = threadIdx.x >> 6;
  const int lane  = threadIdx.x & 63;
  const int laneq = lane & 15;
  const int quad  = lane >> 4;
  const int L = g, H = 127 - g;
  const int mL = (L + 1) >> 1, mH = (H + 1) >> 1;
  const int d   = laneq & 7;
  const bool is8 = (laneq == 8);

  const uint4* Kg = (const uint4*)Kb + (size_t)bh * 2048;
  const uint4* Qg = (const uint4*)Qb + (size_t)bh * 2048;
  const unsigned short* Vtbh = (const unsigned short*)Vb + (size_t)bh * SEQ * HDIM;

  // Q B-frags: lanes<16 hold the 8-dim row in quad 0 (k=0..7); zero others
  U16x8 qfl, qfh;
  {
    const uint4 rl = Qg[16 * L + laneq];
    const uint4 rh = Qg[16 * H + laneq];
    qfl.u = (lane < 16) ? rl : make_uint4(0u, 0u, 0u, 0u);
    qfh.u = (lane < 16) ? rh : make_uint4(0u, 0u, 0u, 0u);
  }

  float4v accL = {0.f, 0.f, 0.f, 0.f};
  float4v accH = {0.f, 0.f, 0.f, 0.f};

  if (w == 0) {
    // k-tiles [0,mL) dual (L+H), [mL,mH) H-only; no diags; prefetch 1 deep
    U16x8 kf; kf.u = Kg[laneq];
    short4v vf = load_vfrag(Vtbh, 0, quad, d, is8);
    #pragma unroll 2
    for (int t = 0; t < mH; ++t) {
      U16x8 kn; kn.u = Kg[16 * (t + 1) + laneq];  // t+1 <= mH <= 64: in-bounds
      short4v vn = load_vfrag(Vtbh, t + 1, quad, d, is8);
      if (t < mL) accL = attn_step<false>(kf.s, qfl.s, vf, accL, laneq, quad);
      accH = attn_step<false>(kf.s, qfh.s, vf, accH, laneq, quad);
      kf = kn; vf = vn;
    }
  } else {
    // L segment: [mL, L], diag at L
    U16x8 kf; kf.u = Kg[16 * mL + laneq];
    short4v vf = load_vfrag(Vtbh, mL, quad, d, is8);
    #pragma unroll 2
    for (int t = mL; t < L; ++t) {
      U16x8 kn; kn.u = Kg[16 * (t + 1) + laneq];
      short4v vn = load_vfrag(Vtbh, t + 1, quad, d, is8);
      accL = attn_step<false>(kf.s, qfl.s, vf, accL, laneq, quad);
      kf = kn; vf = vn;
    }
    accL = attn_step<true>(kf.s, qfl.s, vf, accL, laneq, quad);
    // H segment: [mH, H], diag at H
    kf.u = Kg[16 * mH + laneq];
    vf = load_vfrag(Vtbh, mH, quad, d, is8);
    #pragma unroll 2
    for (int t = mH; t < H; ++t) {
      U16x8 kn; kn.u = Kg[16 * (t + 1) + laneq];  // t+1 <= H = 127: in-bounds
      short4v vn = load_vfrag(Vtbh, t + 1, quad, d, is8);
      accH = attn_step<false>(kf.s, qfh.s, vf, accH, laneq, quad);
      kf = kn; vf = vn;
    }
    accH = attn_step<true>(kf.s, qfh.s, vf, accH, laneq, quad);

    *(float4*)&cmb[0][lane][0] = make_float4(accL[0], accL[1], accL[2], accL[3]);
    *(float4*)&cmb[1][lane][0] = make_float4(accH[0], accH[1], accH[2], accH[3]);
  }
  __syncthreads();

  if (w == 0) {
    const float4 pL = *(const float4*)&cmb[0][lane][0];
    const float4 pH = *(const float4*)&cmb[1][lane][0];
    accL[0] += pL.x; accL[1] += pL.y; accL[2] += pL.z; accL[3] += pL.w;
    accH[0] += pH.x; accH[1] += pH.y; accH[2] += pH.z; accH[3] += pH.w;
    epilogue(accL, L, bh, laneq, quad, out);
    epilogue(accH, H, bh, laneq, quad, out);
  }
}

// ---------------------------------------------------------------------------
extern "C" void kernel_launch(void* const* d_in, const int* in_sizes, int n_in,
                              void* d_out, int out_size, void* d_ws, size_t ws_size,
                              hipStream_t stream)
{
  const float* x  = (const float*)d_in[0];
  const float* Wq = (const float*)d_in[1];
  const float* bq = (const float*)d_in[2];
  const float* Wk = (const float*)d_in[3];
  const float* bk = (const float*)d_in[4];
  const float* Wv = (const float*)d_in[5];
  const float* bv = (const float*)d_in[6];
  const float* Wo = (const float*)d_in[7];
  const float* bo = (const float*)d_in[8];

  float* ws = (float*)d_ws;
  // layout: Wb bf16 4x128x128 (128KB in reserved 256KB) | attn 1048576 f |
  //         Qb, Kb, Vt 524288 dwords each
  unsigned short* Wb = (unsigned short*)ws;
  float*    attn = ws + 65536;
  unsigned* Qb   = (unsigned*)(ws + 65536 + 1048576);
  unsigned* Kb   = Qb + (size_t)524288;
  unsigned* Vb   = Kb + (size_t)524288;

  cast4_kernel<<<dim3(16, 4), 256, 0, stream>>>(Wq, Wk, Wv, Wo, Wb);
  qkv_kernel<<<dim3(NROW / 16, 3), 256, 0, stream>>>(x, Wb, bq, bk, bv, Qb, Kb, Vb);
  attn_kernel<<<dim3(4096), 128, 0, stream>>>(Qb, Kb, Vb, attn);
  oproj_kernel<<<dim3(NROW / 16), 256, 0, stream>>>(attn, Wb + 3 * EDIM * EDIM, bo,
                                                    (float*)d_out);
}

// Round 10
// 121.834 us; speedup vs baseline: 5.4684x; 1.0106x over previous
//
#include <hip/hip_runtime.h>
#include <math.h>

#define EDIM 128
#define NHEAD 16
#define HDIM 8
#define SEQ 2048
#define BATCH 4
#define NROW (BATCH*SEQ)            // 8192
// -scale*log2(e): folded into Q at projection time so sigmoid = rcp(1+exp2(dot))
#define QNEG (-0.35355339059327373f * 1.4426950408889634f)

#if __has_builtin(__builtin_amdgcn_exp2f)
#define EXP2F(x) __builtin_amdgcn_exp2f(x)
#else
#define EXP2F(x) exp2f(x)
#endif
#define RCPF(x) __builtin_amdgcn_rcpf(x)

typedef __attribute__((ext_vector_type(8))) short short8v;
typedef __attribute__((ext_vector_type(4))) short short4v;
typedef __attribute__((ext_vector_type(4))) float float4v;

union U16x8 { uint4 u; short8v s; };
union U16x4 { uint2 u; short4v s; };

#if __has_builtin(__builtin_amdgcn_mfma_f32_16x16x16bf16_1k)
#define MFMA_PV(a,b,c) __builtin_amdgcn_mfma_f32_16x16x16bf16_1k(a,b,c,0,0,0)
#else
static __device__ __forceinline__ float4v mfma_pv_asm(short4v a, short4v b, float4v c) {
  float4v d;
  asm("v_mfma_f32_16x16x16_bf16 %0, %1, %2, %3" : "=v"(d) : "v"(a), "v"(b), "v"(c));
  return d;
}
#define MFMA_PV(a,b,c) mfma_pv_asm(a,b,c)
#endif

// pack two floats to bf16x2, round-to-nearest-even-ish (values finite)
__device__ __forceinline__ unsigned pk_bf16(float a, float b) {
  unsigned ua = __float_as_uint(a), ub = __float_as_uint(b);
  unsigned lo = (ua + 0x7fffu + ((ua >> 16) & 1u)) >> 16;
  unsigned hi = (ub + 0x7fffu + ((ub >> 16) & 1u)) & 0xffff0000u;
  return lo | hi;
}

// A-frags from swizzled LDS: A lane l: A[m=l&15][k=(l>>4)*8+j]
__device__ __forceinline__
void afrags(const unsigned short* xs, int lq, int qd, short8v a[4])
{
  #pragma unroll
  for (int kk = 0; kk < 4; ++kk) {
    const unsigned addr =
        (unsigned)(lq * 256 + kk * 64 + qd * 16) ^ (unsigned)((lq & 7) << 4);
    a[kk] = *(const short8v*)((const char*)xs + addr);
  }
}

// ---------------------------------------------------------------------------
// 32-row x 128-col MFMA projection block, W staged per-block into LDS.
//  - W staged fp32->bf16 COALESCED into XOR-swizzled wlds[128][128] (32 KB);
//    B-frags then come from ds_read_b128 (no 32-line global gathers).
//  - X rows staged fp32->bf16 into swizzled xs[32][128] (8 KB).
//  - Per wave: 8 B-frag ds_reads held in regs, reused over 2 row-tiles
//    (4 A-frag ds_reads + 8 MFMA each) -> 16 MFMA/wave.
//   B lane l: B[k=(l>>4)*8+j][n=l&15] = W[n][k]   D lane l: D[(l>>4)*4+r][l&15]
// MODE 0: Q*QNEG -> bf16 [bh][s][8] (per-wave LDS bounce -> 256B uint4 stores)
// MODE 1: K      -> bf16 [bh][s][8] (same bounce)
// MODE 2: V -> Vt[bh][t=s>>4][d][si] (coalesced uint2)
// MODE 3: fp32 [rows][128] (final output)
// ---------------------------------------------------------------------------
template<int MODE>
__device__ __forceinline__
void proj32(const float* __restrict__ X, const float* __restrict__ W,
            const float* __restrict__ bias, void* __restrict__ out,
            int row0, int tid,
            unsigned short* wlds, unsigned short* xs, unsigned short* bnc)
{
  // ---- stage W: 2 threads per row, 64 cols (16 float4) each, coalesced ----
  {
    const int n = tid >> 1, h = (tid & 1) * 64;
    const float4* src = (const float4*)(W + (size_t)n * EDIM + h);
    const unsigned xr = (unsigned)((n & 7) << 4);
    #pragma unroll
    for (int j = 0; j < 8; ++j) {
      const float4 f0 = src[2 * j], f1 = src[2 * j + 1];
      const uint4 v = make_uint4(pk_bf16(f0.x, f0.y), pk_bf16(f0.z, f0.w),
                                 pk_bf16(f1.x, f1.y), pk_bf16(f1.z, f1.w));
      *(uint4*)((char*)wlds + ((unsigned)(n * 256 + h * 2 + j * 16) ^ xr)) = v;
    }
  }
  // ---- stage X: 8 threads per row (32 rows), 16 cols each ----
  {
    const int r = tid >> 3, c = tid & 7;
    const float4* src = (const float4*)(X + (size_t)(row0 + r) * EDIM + c * 16);
    const unsigned xr = (unsigned)((r & 7) << 4);
    const float4 f0 = src[0], f1 = src[1], f2 = src[2], f3 = src[3];
    const uint4 v0 = make_uint4(pk_bf16(f0.x, f0.y), pk_bf16(f0.z, f0.w),
                                pk_bf16(f1.x, f1.y), pk_bf16(f1.z, f1.w));
    const uint4 v1 = make_uint4(pk_bf16(f2.x, f2.y), pk_bf16(f2.z, f2.w),
                                pk_bf16(f3.x, f3.y), pk_bf16(f3.z, f3.w));
    *(uint4*)((char*)xs + ((unsigned)(r * 256 + c * 32) ^ xr)) = v0;
    *(uint4*)((char*)xs + ((unsigned)(r * 256 + c * 32 + 16) ^ xr)) = v1;
  }
  __syncthreads();

  const int lane = tid & 63, wv = tid >> 6;
  const int lq = lane & 15, qd = lane >> 4;
  const int n0 = wv * 32;

  // ---- B-frags once per wave (two 16-col tiles) ----
  short8v b0[4], b1[4];
  #pragma unroll
  for (int kk = 0; kk < 4; ++kk) {
    const unsigned ad = (unsigned)((n0 + lq) * 256 + kk * 64 + qd * 16)
                      ^ (unsigned)((lq & 7) << 4);
    b0[kk] = *(const short8v*)((const char*)wlds + ad);
    b1[kk] = *(const short8v*)((const char*)wlds + ad + 4096);  // +16 rows
  }

  const int nA = n0 + lq, nB = nA + 16;
  const float bzA = bias[nA], bzB = bias[nB];
  const int b_ = row0 >> 11;

  #pragma unroll
  for (int rt = 0; rt < 2; ++rt) {
    const int rowt = row0 + rt * 16;
    short8v a[4];
    afrags(xs + rt * 2048, lq, qd, a);

    float4v D0 = {0.f, 0.f, 0.f, 0.f}, D1 = {0.f, 0.f, 0.f, 0.f};
    #pragma unroll
    for (int kk = 0; kk < 4; ++kk) {
      D0 = __builtin_amdgcn_mfma_f32_16x16x32_bf16(a[kk], b0[kk], D0, 0, 0, 0);
      D1 = __builtin_amdgcn_mfma_f32_16x16x32_bf16(a[kk], b1[kk], D1, 0, 0, 0);
    }

    if (MODE == 3) {
      float* of = (float*)out + (size_t)(rowt + qd * 4) * EDIM + nA;
      #pragma unroll
      for (int r = 0; r < 4; ++r) {
        of[r * EDIM]      = D0[r] + bzA;
        of[r * EDIM + 16] = D1[r] + bzB;
      }
      continue;
    }

    const int srel = rowt & (SEQ - 1);

    if (MODE == 2) {
      // Vt[bh][tg][d][si]: row-tile = one 16-s tile; si = qd*4 + r.
      const int tg = srel >> 4;
      unsigned short* oU = (unsigned short*)out;
      {
        const int bh = b_ * NHEAD + (nA >> 3), dv = nA & 7;
        uint2 p;
        p.x = pk_bf16(D0[0] + bzA, D0[1] + bzA);
        p.y = pk_bf16(D0[2] + bzA, D0[3] + bzA);
        *(uint2*)(oU + (size_t)bh * (SEQ * HDIM) + tg * 128 + dv * 16 + qd * 4) = p;
      }
      {
        const int bh = b_ * NHEAD + (nB >> 3), dv = nB & 7;
        uint2 p;
        p.x = pk_bf16(D1[0] + bzB, D1[1] + bzB);
        p.y = pk_bf16(D1[2] + bzB, D1[3] + bzB);
        *(uint2*)(oU + (size_t)bh * (SEQ * HDIM) + tg * 128 + dv * 16 + qd * 4) = p;
      }
      continue;
    }

    // MODE 0/1: bounce both 16x16 tiles through padded LDS ([16][20] u16),
    // then contiguous 256B uint4 stores (one [bh][s][8] row per lane).
    #pragma unroll
    for (int r = 0; r < 4; ++r) {
      float vA = D0[r] + bzA, vB = D1[r] + bzB;
      if (MODE == 0) { vA *= QNEG; vB *= QNEG; }
      const int m = qd * 4 + r;
      bnc[m * 20 + lq]       = (unsigned short)pk_bf16(vA, 0.f);
      bnc[320 + m * 20 + lq] = (unsigned short)pk_bf16(vB, 0.f);
    }
    __syncthreads();                              // LDS write->read order

    const int mm   = lane & 15;
    const int half = (lane >> 4) & 1;
    const int tile = lane >> 5;
    const unsigned short* sp = bnc + tile * 320 + mm * 20 + half * 8;
    const uint2 w0 = *(const uint2*)sp;
    const uint2 w1 = *(const uint2*)(sp + 4);
    const int bh = b_ * NHEAD + wv * 4 + tile * 2 + half;
    unsigned short* dp = (unsigned short*)out + ((size_t)bh * SEQ + srel + mm) * 8;
    *(uint4*)dp = make_uint4(w0.x, w0.y, w1.x, w1.y);
    __syncthreads();                              // bnc reuse guard (next rt)
  }
}

__global__ __launch_bounds__(256)
void qkv_kernel(const float* __restrict__ X,
                const float* __restrict__ Wq, const float* __restrict__ Wk,
                const float* __restrict__ Wv,
                const float* __restrict__ bq, const float* __restrict__ bk,
                const float* __restrict__ bv,
                unsigned* __restrict__ qb, unsigned* __restrict__ kb,
                unsigned* __restrict__ vb)
{
  __shared__ __align__(16) unsigned short wlds[16384];   // 32 KB
  __shared__ __align__(16) unsigned short xs[4096];      // 8 KB
  __shared__ __align__(16) unsigned short bnc[4 * 640];  // 5 KB
  const int tid = threadIdx.x;
  const int row0 = blockIdx.x * 32;
  unsigned short* myb = bnc + (tid >> 6) * 640;
  const int m = blockIdx.y;
  if (m == 0)      proj32<0>(X, Wq, bq, (void*)qb, row0, tid, wlds, xs, myb);
  else if (m == 1) proj32<1>(X, Wk, bk, (void*)kb, row0, tid, wlds, xs, myb);
  else             proj32<2>(X, Wv, bv, (void*)vb, row0, tid, wlds, xs, myb);
}

__global__ __launch_bounds__(256)
void oproj_kernel(const float* __restrict__ A, const float* __restrict__ Wo,
                  const float* __restrict__ bo, float* __restrict__ out)
{
  __shared__ __align__(16) unsigned short wlds[16384];   // 32 KB
  __shared__ __align__(16) unsigned short xs[4096];      // 8 KB
  proj32<3>(A, Wo, bo, (void*)out, blockIdx.x * 32, threadIdx.x, wlds, xs, nullptr);
}

// ---------------------------------------------------------------------------
// One 16q x 16k MFMA step.  (round-0 verified sigmoid path)
// S^T = mfma_16x16x32_bf16(A=K-rows, B=Q-frag) -> C[key][q]. Sigmoid
// elementwise; C-register reinterpreted as A-operand of mfma_16x16x16 gives
// the UN-transposed P, so out[q][d] = mfma(A=P, B=V-frag, acc). V-frag col 8
// is forced to 1.0 so acc col 8 accumulates the denominator.
// ---------------------------------------------------------------------------
template<bool DIAG>
__device__ __forceinline__
float4v attn_step(short8v kf, short8v qf, short4v vf, float4v acc,
                  int laneq, int quad)
{
  const float4v z = {0.f, 0.f, 0.f, 0.f};
  float4v st = __builtin_amdgcn_mfma_f32_16x16x32_bf16(kf, qf, z, 0, 0, 0);
  unsigned rb[4];
  #pragma unroll
  for (int r = 0; r < 4; ++r) {
    float s = RCPF(1.f + EXP2F(st[r]));           // Q carries -scale*log2e
    if (DIAG) s = (4 * quad + r <= laneq) ? s : 0.f;  // exact: sigma(-1e9)==0
    rb[r] = __float_as_uint(s) + 0x8000u;         // round-half-up to bf16
  }
  U16x4 p;
  p.u.x = __builtin_amdgcn_perm(rb[1], rb[0], 0x07060302u);
  p.u.y = __builtin_amdgcn_perm(rb[3], rb[2], 0x07060302u);
  return MFMA_PV(p.s, vf, acc);                   // A = P[q][k], B = V[k][d]
}

// V-frag loader from tile-blocked Vt[bh][t][d][si]: ONE dwordx2 from a
// contiguous 256B tile block. lanes laneq==8 -> bf16 1.0 (denominator col).
__device__ __forceinline__
short4v load_vfrag(const unsigned short* __restrict__ Vtbh, int t,
                   int quad, int d, bool is8)
{
  const unsigned short* p = Vtbh + t * 128 + d * 16 + 4 * quad;
  const uint2 v = *(const uint2*)p;
  U16x4 vf;
  vf.u.x = is8 ? 0x3F803F80u : v.x;
  vf.u.y = is8 ? 0x3F803F80u : v.y;
  return vf.s;
}

// epilogue: den = acc col 8; normalize and store rows of tile T
__device__ __forceinline__
void epilogue(float4v acc, int T, int bh, int laneq, int quad,
              float* __restrict__ out)
{
  const int b_ = bh >> 4, h = bh & 15;
  const int pidx = (quad * 16 + 8) << 2;          // lane holding col 8
  #pragma unroll
  for (int r = 0; r < 4; ++r) {
    const float den = __int_as_float(
        __builtin_amdgcn_ds_bpermute(pidx, __float_as_int(acc[r])));
    const float val = acc[r] * RCPF(den);         // den > 0
    const int row = 16 * T + 4 * quad + r;
    if (laneq < 8)
      out[(size_t)(b_ * SEQ + row) * EDIM + h * HDIM + laneq] = val;
  }
}

// ---------------------------------------------------------------------------
// Causal sigmoid-attention v11 (unchanged control: 42us): split-K x2
// fold-pair schedule, dwordx2 V-frags from tile-blocked Vt.
// blockIdx low 6 bits = bh -> XCD = bh%8 (L2 locality).
// ---------------------------------------------------------------------------
__global__ __launch_bounds__(128, 8)
void attn_kernel(const unsigned* __restrict__ Qb, const unsigned* __restrict__ Kb,
                 const unsigned* __restrict__ Vb, float* __restrict__ out)
{
  __shared__ float cmb[2][64][4];                 // 2 KB

  const int bh    = blockIdx.x & 63;
  const int g     = blockIdx.x >> 6;              // 0..63
  const int w     = threadIdx.x >> 6;
  const int lane  = threadIdx.x & 63;
  const int laneq = lane & 15;
  const int quad  = lane >> 4;
  const int L = g, H = 127 - g;
  const int mL = (L + 1) >> 1, mH = (H + 1) >> 1;
  const int d   = laneq & 7;
  const bool is8 = (laneq == 8);

  const uint4* Kg = (const uint4*)Kb + (size_t)bh * 2048;
  const uint4* Qg = (const uint4*)Qb + (size_t)bh * 2048;
  const unsigned short* Vtbh = (const unsigned short*)Vb + (size_t)bh * SEQ * HDIM;

  // Q B-frags: lanes<16 hold the 8-dim row in quad 0 (k=0..7); zero others
  U16x8 qfl, qfh;
  {
    const uint4 rl = Qg[16 * L + laneq];
    const uint4 rh = Qg[16 * H + laneq];
    qfl.u = (lane < 16) ? rl : make_uint4(0u, 0u, 0u, 0u);
    qfh.u = (lane < 16) ? rh : make_uint4(0u, 0u, 0u, 0u);
  }

  float4v accL = {0.f, 0.f, 0.f, 0.f};
  float4v accH = {0.f, 0.f, 0.f, 0.f};

  if (w == 0) {
    // k-tiles [0,mL) dual (L+H), [mL,mH) H-only; no diags; prefetch 1 deep
    U16x8 kf; kf.u = Kg[laneq];
    short4v vf = load_vfrag(Vtbh, 0, quad, d, is8);
    #pragma unroll 2
    for (int t = 0; t < mH; ++t) {
      U16x8 kn; kn.u = Kg[16 * (t + 1) + laneq];  // t+1 <= mH <= 64: in-bounds
      short4v vn = load_vfrag(Vtbh, t + 1, quad, d, is8);
      if (t < mL) accL = attn_step<false>(kf.s, qfl.s, vf, accL, laneq, quad);
      accH = attn_step<false>(kf.s, qfh.s, vf, accH, laneq, quad);
      kf = kn; vf = vn;
    }
  } else {
    // L segment: [mL, L], diag at L
    U16x8 kf; kf.u = Kg[16 * mL + laneq];
    short4v vf = load_vfrag(Vtbh, mL, quad, d, is8);
    #pragma unroll 2
    for (int t = mL; t < L; ++t) {
      U16x8 kn; kn.u = Kg[16 * (t + 1) + laneq];
      short4v vn = load_vfrag(Vtbh, t + 1, quad, d, is8);
      accL = attn_step<false>(kf.s, qfl.s, vf, accL, laneq, quad);
      kf = kn; vf = vn;
    }
    accL = attn_step<true>(kf.s, qfl.s, vf, accL, laneq, quad);
    // H segment: [mH, H], diag at H
    kf.u = Kg[16 * mH + laneq];
    vf = load_vfrag(Vtbh, mH, quad, d, is8);
    #pragma unroll 2
    for (int t = mH; t < H; ++t) {
      U16x8 kn; kn.u = Kg[16 * (t + 1) + laneq];  // t+1 <= H = 127: in-bounds
      short4v vn = load_vfrag(Vtbh, t + 1, quad, d, is8);
      accH = attn_step<false>(kf.s, qfh.s, vf, accH, laneq, quad);
      kf = kn; vf = vn;
    }
    accH = attn_step<true>(kf.s, qfh.s, vf, accH, laneq, quad);

    *(float4*)&cmb[0][lane][0] = make_float4(accL[0], accL[1], accL[2], accL[3]);
    *(float4*)&cmb[1][lane][0] = make_float4(accH[0], accH[1], accH[2], accH[3]);
  }
  __syncthreads();

  if (w == 0) {
    const float4 pL = *(const float4*)&cmb[0][lane][0];
    const float4 pH = *(const float4*)&cmb[1][lane][0];
    accL[0] += pL.x; accL[1] += pL.y; accL[2] += pL.z; accL[3] += pL.w;
    accH[0] += pH.x; accH[1] += pH.y; accH[2] += pH.z; accH[3] += pH.w;
    epilogue(accL, L, bh, laneq, quad, out);
    epilogue(accH, H, bh, laneq, quad, out);
  }
}

// ---------------------------------------------------------------------------
extern "C" void kernel_launch(void* const* d_in, const int* in_sizes, int n_in,
                              void* d_out, int out_size, void* d_ws, size_t ws_size,
                              hipStream_t stream)
{
  const float* x  = (const float*)d_in[0];
  const float* Wq = (const float*)d_in[1];
  const float* bq = (const float*)d_in[2];
  const float* Wk = (const float*)d_in[3];
  const float* bk = (const float*)d_in[4];
  const float* Wv = (const float*)d_in[5];
  const float* bv = (const float*)d_in[6];
  const float* Wo = (const float*)d_in[7];
  const float* bo = (const float*)d_in[8];

  float* ws = (float*)d_ws;
  // layout: (64K floats reserved) | attn 1048576 f | Qb, Kb, Vt 524288 dw each
  float*    attn = ws + 65536;
  unsigned* Qb   = (unsigned*)(ws + 65536 + 1048576);
  unsigned* Kb   = Qb + (size_t)524288;
  unsigned* Vb   = Kb + (size_t)524288;

  qkv_kernel<<<dim3(NROW / 32, 3), 256, 0, stream>>>(x, Wq, Wk, Wv, bq, bk, bv,
                                                     Qb, Kb, Vb);
  attn_kernel<<<dim3(4096), 128, 0, stream>>>(Qb, Kb, Vb, attn);
  oproj_kernel<<<dim3(NROW / 32), 256, 0, stream>>>(attn, Wo, bo, (float*)d_out);
}